// Round 10
// baseline (396.895 us; speedup 1.0000x reference)
//
#include <hip/hip_runtime.h>
#include <hip/hip_bf16.h>

typedef __hip_bfloat16 bf16;
typedef __attribute__((ext_vector_type(8))) short short8;
typedef __attribute__((ext_vector_type(8))) unsigned short ushort8;
typedef __attribute__((ext_vector_type(4))) float floatx4;

#define BATCH 2
#define S_LEN 2048
#define NHEAD 16
#define HD 128
#define HIDDEN 2048
// softmax scale folded into Q at GEMM1 epilogue: 1/sqrt(128) * log2(e)
#define QSCALE 0.12754435f
// fixed softmax offset (cancels in O = sum(p v)/sum(p)); scores |s|<~8 << 12
#define FOFF 12.0f

static __device__ __forceinline__ unsigned short f2bf(float f) {
    union { float f; unsigned int u; } c; c.f = f;
    unsigned int u = c.u;
    unsigned int rounded = u + 0x7FFF + ((u >> 16) & 1);   // RNE
    return (unsigned short)(rounded >> 16);
}

// compiler-opaque LDS read (no auto waitcnt; caller places lgkmcnt+sched_barrier)
static __device__ __forceinline__ short8 lds_read16(unsigned off) {
    short8 r;
    asm volatile("ds_read_b128 %0, %1" : "=v"(r) : "v"(off));
    return r;
}

// ---------------------------------------------------------------------------
// Elementwise cast fp32 -> bf16, 8 elements/thread
// ---------------------------------------------------------------------------
__global__ __launch_bounds__(256) void cast_f32_bf16(const float* __restrict__ src,
                                                     bf16* __restrict__ dst) {
    int i = (blockIdx.x * 256 + threadIdx.x) * 8;
    float4 a = *(const float4*)&src[i];
    float4 b = *(const float4*)&src[i + 4];
    ushort8 o;
    o[0] = f2bf(a.x); o[1] = f2bf(a.y); o[2] = f2bf(a.z); o[3] = f2bf(a.w);
    o[4] = f2bf(b.x); o[5] = f2bf(b.y); o[6] = f2bf(b.z); o[7] = f2bf(b.w);
    *(ushort8*)&dst[i] = o;
}

// ---------------------------------------------------------------------------
// Cast+transpose: dst[C x R] (bf16) = src[R x C]^T (fp32)
// ---------------------------------------------------------------------------
__global__ __launch_bounds__(256) void cast_transpose(const float* __restrict__ src,
                                                      bf16* __restrict__ dst,
                                                      int R, int C) {
    __shared__ unsigned short t[32][33];
    int tx = threadIdx.x & 31, ty = threadIdx.x >> 5;  // 32 x 8
    int c0 = blockIdx.x * 32, r0 = blockIdx.y * 32;
#pragma unroll
    for (int i = 0; i < 4; i++) {
        int r = r0 + ty + i * 8;
        t[ty + i * 8][tx] = f2bf(src[(size_t)r * C + c0 + tx]);
    }
    __syncthreads();
#pragma unroll
    for (int i = 0; i < 4; i++) {
        int cc = c0 + ty + i * 8;
        ((unsigned short*)dst)[(size_t)cc * R + r0 + tx] = t[tx][ty + i * 8];
    }
}

// ---------------------------------------------------------------------------
// Shared GEMM: 128x128 / BK=64, 256 threads (4 waves, wave-tile 64x64),
// LDS 64 KiB double-buffer -> 2 blocks/CU. MEASURED R8: merged GEMM1 135.5 us
// (was 164.7 at 1 block/CU), MfmaUtil 32%, conflicts 0 -- cross-block overlap
// (m97/m114 mechanism) confirmed as the lever. FROZEN this round.
//   per K-tile: issue all 16 ds_reads -> lgkmcnt(4) -> 16 MFMA -> lgkmcnt(0)
//   -> 16 MFMA -> BAR -> stage(t+2) -> vmcnt(8) -> BAR.
//   EPI=0: scatter QKV epilogue. EPI=1: C = acc + bias, fp32, stride ntN*128.
// ---------------------------------------------------------------------------
#define GK 2048
#define NT 32

#define BAR __builtin_amdgcn_s_barrier()
#define SCHED0 __builtin_amdgcn_sched_barrier(0)

static __device__ __forceinline__ void gll(const bf16* g, char* l) {
    __builtin_amdgcn_global_load_lds(
        (const __attribute__((address_space(1))) void*)g,
        (__attribute__((address_space(3))) void*)l, 16, 0, 0);
}

#define STG8(s)                                                                 \
    do {                                                                        \
        _Pragma("unroll")                                                       \
        for (int ld = 0; ld < 4; ld++) {                                        \
            gll(pA + (size_t)(ld * 8) * GK + (s) * 64,                          \
                lA + ((s) & 1) * 16384 + wave * 4096 + ld * 1024);              \
            gll(pB + (size_t)(ld * 8) * GK + (s) * 64,                          \
                lB + ((s) & 1) * 16384 + wave * 4096 + ld * 1024);              \
        }                                                                       \
    } while (0)

#define RD_A(i, ks) aF[i][ks] = lds_read16(Ab + ((unsigned)((wm * 64 + (i) * 16 + lr) << 7)) + ((unsigned)(((ks) * 64 + quad * 16)) ^ axor));
#define RD_B(j, ks) bF[j][ks] = lds_read16(Bb + ((unsigned)((wn * 64 + (j) * 16 + lr) << 7)) + ((unsigned)(((ks) * 64 + quad * 16)) ^ axor));

template <int EPI>
__global__ __launch_bounds__(256, 2) void gemm128(const bf16* __restrict__ A,
                                                  const bf16* __restrict__ Bt,
                                                  const float* __restrict__ bias,
                                                  bf16* __restrict__ Qb,
                                                  bf16* __restrict__ Kb,
                                                  bf16* __restrict__ Vt,
                                                  float* __restrict__ Cout,
                                                  int ntN) {
    __shared__ __align__(16) bf16 Asm[2][128 * 64];   // 32 KiB
    __shared__ __align__(16) bf16 Bsm[2][128 * 64];   // 32 KiB

    int tid = threadIdx.x;
    int wave = tid >> 6, lane = tid & 63;
    int quad = lane >> 4, lr = lane & 15;
    int wm = wave >> 1, wn = wave & 1;
    unsigned axor = (unsigned)((lr & 7) << 4);

    // bijective XCD swizzle (gridDim.x % 8 == 0)
    int nwg = gridDim.x;
    int cpx = nwg >> 3;
    int bid = blockIdx.x;
    int swz = (bid & 7) * cpx + (bid >> 3);
    int mt = swz / ntN, nt = swz - mt * ntN;
    int m0 = mt * 128, n0 = nt * 128;

    // staging: LDS linear dest (HW adds lane*16); inverse-swizzled global src
    int srow = wave * 32 + (lane >> 3);
    int scol = ((lane & 7) ^ ((lane >> 3) & 7)) * 8;
    const bf16* pA = A + (size_t)(m0 + srow) * GK + scol;
    const bf16* pB = Bt + (size_t)(n0 + srow) * GK + scol;
    char* lA = (char*)&Asm[0][0];
    char* lB = (char*)&Bsm[0][0];

    unsigned aBase0 = (unsigned)(size_t)(__attribute__((address_space(3))) char*)lA;
    unsigned bBase0 = (unsigned)(size_t)(__attribute__((address_space(3))) char*)lB;

    const floatx4 fzero = {0.f, 0.f, 0.f, 0.f};
    floatx4 acc[4][4];
#pragma unroll
    for (int i = 0; i < 4; i++)
#pragma unroll
        for (int j = 0; j < 4; j++) acc[i][j] = fzero;

    short8 aF[4][2], bF[4][2];

    // prologue: stage K-tiles 0 and 1 (16 loads); wait first 8 (K0 landed)
    STG8(0);
    STG8(1);
    asm volatile("s_waitcnt vmcnt(8)" ::: "memory");
    BAR;

    for (int t = 0; t < NT; ++t) {
        unsigned Ab = aBase0 + (unsigned)((t & 1) * 16384);
        unsigned Bb = bBase0 + (unsigned)((t & 1) * 16384);

        // issue all 16 fragment reads: b01 (4), a0-3 (8), b23 (4)
        RD_B(0, 0) RD_B(0, 1) RD_B(1, 0) RD_B(1, 1)
        RD_A(0, 0) RD_A(0, 1) RD_A(1, 0) RD_A(1, 1)
        RD_A(2, 0) RD_A(2, 1) RD_A(3, 0) RD_A(3, 1)
        RD_B(2, 0) RD_B(2, 1) RD_B(3, 0) RD_B(3, 1)

        // oldest 12 (b01 + a) retired; b23 still draining under the MFMAs
        asm volatile("s_waitcnt lgkmcnt(4)" ::: "memory");
        SCHED0;
        __builtin_amdgcn_s_setprio(1);
#pragma unroll
        for (int ks = 0; ks < 2; ks++)
#pragma unroll
            for (int i = 0; i < 4; i++)
#pragma unroll
                for (int j = 0; j < 2; j++)
                    acc[i][j] = __builtin_amdgcn_mfma_f32_16x16x32_bf16(
                        aF[i][ks], bF[j][ks], acc[i][j], 0, 0, 0);
        __builtin_amdgcn_s_setprio(0);

        asm volatile("s_waitcnt lgkmcnt(0)" ::: "memory");
        SCHED0;
        __builtin_amdgcn_s_setprio(1);
#pragma unroll
        for (int ks = 0; ks < 2; ks++)
#pragma unroll
            for (int i = 0; i < 4; i++)
#pragma unroll
                for (int j = 2; j < 4; j++)
                    acc[i][j] = __builtin_amdgcn_mfma_f32_16x16x32_bf16(
                        aF[i][ks], bF[j][ks], acc[i][j], 0, 0, 0);
        __builtin_amdgcn_s_setprio(0);

        // all reads of tile t retired (lgkm0 above) -> safe to let stages land
        BAR;
        SCHED0;
        if (t + 2 < NT) {
            STG8(t + 2);
            SCHED0;
            asm volatile("s_waitcnt vmcnt(8)" ::: "memory");   // t+1 landed
        } else {
            asm volatile("s_waitcnt vmcnt(0)" ::: "memory");
        }
        BAR;
    }

    // ---- epilogue ----
    if (EPI == 0) {
#pragma unroll
        for (int i = 0; i < 4; i++) {
#pragma unroll
            for (int j = 0; j < 4; j++) {
                int gcn = n0 + wn * 64 + j * 16 + lr;
                float bv = bias[gcn];
                int tsel = gcn >> 11, hh = (gcn >> 7) & 15, d = gcn & 127;
#pragma unroll
                for (int reg = 0; reg < 4; reg++) {
                    int gm = m0 + wm * 64 + i * 16 + quad * 4 + reg;
                    float v = acc[i][j][reg] + bv;
                    int bb = gm >> 11, s = gm & 2047;
                    size_t hb = (size_t)(bb * NHEAD + hh);
                    if (tsel == 0) {
                        Qb[(hb * S_LEN + s) * HD + d] = __float2bfloat16(v * QSCALE);
                    } else if (tsel == 1) {
                        Kb[(hb * S_LEN + s) * HD + d] = __float2bfloat16(v);
                    } else {
                        Vt[(hb * HD + d) * S_LEN + s] = __float2bfloat16(v);
                    }
                }
            }
        }
    } else {
        int N = ntN << 7;
#pragma unroll
        for (int i = 0; i < 4; i++) {
#pragma unroll
            for (int j = 0; j < 4; j++) {
                int gcn = n0 + wn * 64 + j * 16 + lr;
                float bv = bias[gcn];
#pragma unroll
                for (int reg = 0; reg < 4; reg++) {
                    int gm = m0 + wm * 64 + i * 16 + quad * 4 + reg;
                    Cout[(size_t)gm * N + gcn] = acc[i][j][reg] + bv;
                }
            }
        }
    }
}

// ---------------------------------------------------------------------------
// Flash attention (causal), fixed-offset softmax (no max/sum shuffles, no
// rescale): p = exp2(s - FOFF); l accumulated via MFMA(P, ones). K/V tiles
// prefetched into registers during compute, ds_write after barrier.
// R9 change: UNPAIRED grid -- one 64-row q-tile per block, grid (16,32,2) =
// 1024 blocks, qt = 31 - blockIdx.y (longest tiles dispatch first so short
// ones pack the tail). __launch_bounds__(256,3): LDS ~41 KiB -> 3 blocks/CU,
// applying the R8-proven cross-block overlap mechanism to attn's serial
// chain (implied MfmaUtil ~13% at 2 blocks/CU).
// ---------------------------------------------------------------------------
#define PSTR 72   // Ps row stride (el)
__global__ __launch_bounds__(256, 3) void attn_kernel(const bf16* __restrict__ Qb,
                                                      const bf16* __restrict__ Kb,
                                                      const bf16* __restrict__ Vt,
                                                      bf16* __restrict__ Obuf) {
    __shared__ __align__(16) bf16 Ks[64 * 128];    // [key][d], chunk^=(key&15)
    __shared__ __align__(16) bf16 Vs[128 * 64];    // [d][key], chunk^=(d&7)
    __shared__ __align__(16) bf16 Ps[4][16 * PSTR];

    int tid = threadIdx.x;
    int wave = tid >> 6, lane = tid & 63;
    int quad = lane >> 4, lr = lane & 15;
    int srow = lane >> 4;
    int head = blockIdx.x, b = blockIdx.z;
    int qt = 31 - blockIdx.y;              // 64-row q-tile index, 0..31
    size_t hb = (size_t)(b * NHEAD + head);
    const bf16* Qbase = Qb + hb * S_LEN * HD;
    const bf16* Kbase = Kb + hb * S_LEN * HD;
    const bf16* Vbase = Vt + hb * (size_t)HD * S_LEN;

    const floatx4 fzero = {0.f, 0.f, 0.f, 0.f};
    const float MASKV = -30000.f;
    short8 ones;
#pragma unroll
    for (int i = 0; i < 8; i++) ones[i] = (short)0x3F80;   // bf16 1.0

    {
        int q0 = qt * 64;
        int niter = qt + 1;                // diagonal tile is the last iter

        short8 qF[4];
#pragma unroll
        for (int kc = 0; kc < 4; kc++)
            qF[kc] = *(const short8*)&Qbase[(size_t)(q0 + wave * 16 + lr) * HD + kc * 32 + quad * 8];

        floatx4 Oacc[8];
        floatx4 lacc = fzero;
#pragma unroll
        for (int dn = 0; dn < 8; dn++) Oacc[dn] = fzero;

        // prefetch tile 0 into registers
        ushort8 kpre[4], vpre[4];
#pragma unroll
        for (int i = 0; i < 4; i++) {
            int rl = wave * 16 + i * 4 + srow;
            int gc = lr ^ (rl & 15);
            kpre[i] = *(const ushort8*)&Kbase[(size_t)rl * HD + gc * 8];
            int vr = wave * 32 + i * 8 + (lane >> 3);
            int gvc = (lane & 7) ^ (vr & 7);
            vpre[i] = *(const ushort8*)&Vbase[(size_t)vr * S_LEN + gvc * 8];
        }

        for (int kt = 0; kt < niter; kt++) {
            __syncthreads();   // previous iteration's LDS reads complete
            // commit prefetched K/V to LDS
#pragma unroll
            for (int i = 0; i < 4; i++) {
                *(ushort8*)&Ks[(wave * 16 + i * 4) * 128 + lane * 8] = kpre[i];
                *(ushort8*)&Vs[(wave * 32 + i * 8) * 64 + lane * 8] = vpre[i];
            }
            __syncthreads();
            // issue prefetch for next tile (lands during this compute)
            if (kt + 1 < niter) {
                int ns0 = (kt + 1) * 64;
#pragma unroll
                for (int i = 0; i < 4; i++) {
                    int rl = wave * 16 + i * 4 + srow;
                    int gc = lr ^ (rl & 15);
                    kpre[i] = *(const ushort8*)&Kbase[(size_t)(ns0 + rl) * HD + gc * 8];
                    int vr = wave * 32 + i * 8 + (lane >> 3);
                    int gvc = (lane & 7) ^ (vr & 7);
                    vpre[i] = *(const ushort8*)&Vbase[(size_t)vr * S_LEN + ns0 + gvc * 8];
                }
            }

            // ---- QK^T: 64 keys for this wave's 16 q-rows ----
            floatx4 sc[4];
#pragma unroll
            for (int nt = 0; nt < 4; nt++) sc[nt] = fzero;
#pragma unroll
            for (int kc = 0; kc < 4; kc++)
#pragma unroll
                for (int nt = 0; nt < 4; nt++) {
                    short8 kf = *(const short8*)&Ks[(nt * 16 + lr) * 128 + (((kc * 4 + quad) ^ lr) & 15) * 8];
                    sc[nt] = __builtin_amdgcn_mfma_f32_16x16x32_bf16(qF[kc], kf, sc[nt], 0, 0, 0);
                }
            // causal mask on the diagonal tile (last iteration; q0 == ks0)
            if (kt == niter - 1) {
#pragma unroll
                for (int nt = 0; nt < 4; nt++)
#pragma unroll
                    for (int reg = 0; reg < 4; reg++) {
                        int qg = wave * 16 + quad * 4 + reg;
                        int kg = nt * 16 + lr;
                        if (kg > qg) sc[nt][reg] = MASKV;
                    }
            }
            // ---- fixed-offset softmax: p = exp2(s - FOFF), no reductions ----
#pragma unroll
            for (int nt = 0; nt < 4; nt++)
#pragma unroll
                for (int reg = 0; reg < 4; reg++) {
                    float pv = __builtin_amdgcn_exp2f(sc[nt][reg] - FOFF);
                    Ps[wave][(quad * 4 + reg) * PSTR + nt * 16 + lr] = __float2bfloat16(pv);
                }
            // ---- PV + l accumulation via ones-MFMA ----
#pragma unroll
            for (int st = 0; st < 2; st++) {
                short8 aP = *(const short8*)&Ps[wave][lr * PSTR + st * 32 + quad * 8];
                lacc = __builtin_amdgcn_mfma_f32_16x16x32_bf16(aP, ones, lacc, 0, 0, 0);
#pragma unroll
                for (int dn = 0; dn < 8; dn++) {
                    short8 vf = *(const short8*)&Vs[(dn * 16 + lr) * 64 + (((st * 4 + quad) ^ (lr & 7)) & 7) * 8];
                    Oacc[dn] = __builtin_amdgcn_mfma_f32_16x16x32_bf16(aP, vf, Oacc[dn], 0, 0, 0);
                }
            }
        }

        // epilogue: O /= l (lacc[reg] = row-sum for row quad*4+reg, any col)
#pragma unroll
        for (int reg = 0; reg < 4; reg++) {
            float inv = 1.0f / lacc[reg];
            int qg = q0 + wave * 16 + quad * 4 + reg;
#pragma unroll
            for (int dn = 0; dn < 8; dn++) {
                int d = dn * 16 + lr;
                Obuf[((size_t)(b * S_LEN + qg)) * HIDDEN + head * HD + d] =
                    __float2bfloat16(Oacc[dn][reg] * inv);
            }
        }
    }
}

// ---------------------------------------------------------------------------
extern "C" void kernel_launch(void* const* d_in, const int* in_sizes, int n_in,
                              void* d_out, int out_size, void* d_ws, size_t ws_size,
                              hipStream_t stream) {
    (void)in_sizes; (void)n_in; (void)out_size; (void)ws_size;
    const float* x    = (const float*)d_in[0];
    const float* Wqkv = (const float*)d_in[1];
    const float* bqkv = (const float*)d_in[2];
    const float* Wo   = (const float*)d_in[3];
    const float* bo   = (const float*)d_in[4];
    float* out = (float*)d_out;

    bf16* ws = (bf16*)d_ws;
    bf16* Xb    = ws;                                   // 8.39M el
    bf16* Obuf  = ws;                                   // alias (Xb dead after GEMM1)
    bf16* WqkvT = ws + (size_t)8388608;                 // 12.58M el
    bf16* WoT   = WqkvT;                                // alias (dead after GEMM1)
    bf16* Qb    = WqkvT + (size_t)12582912;
    bf16* Kb    = Qb + (size_t)8388608;
    bf16* Vt    = Kb + (size_t)8388608;

    cast_f32_bf16<<<4096, 256, 0, stream>>>(x, Xb);
    cast_transpose<<<dim3(192, 64), 256, 0, stream>>>(Wqkv, WqkvT, 2048, 6144);
    gemm128<0><<<dim3(1536), dim3(256), 0, stream>>>(Xb, WqkvT, bqkv, Qb, Kb, Vt, nullptr, 48);
    cast_transpose<<<dim3(64, 64), 256, 0, stream>>>(Wo, WoT, 2048, 2048);
    attn_kernel<<<dim3(16, 32, 2), 256, 0, stream>>>(Qb, Kb, Vt, Obuf);
    gemm128<1><<<dim3(512), dim3(256), 0, stream>>>(Obuf, WoT, bo, nullptr, nullptr, nullptr, out, 16);
}

// Round 11
// 372.181 us; speedup vs baseline: 1.0664x; 1.0664x over previous
//
#include <hip/hip_runtime.h>
#include <hip/hip_bf16.h>

typedef __hip_bfloat16 bf16;
typedef __attribute__((ext_vector_type(8))) short short8;
typedef __attribute__((ext_vector_type(8))) unsigned short ushort8;
typedef __attribute__((ext_vector_type(4))) float floatx4;

#define BATCH 2
#define S_LEN 2048
#define NHEAD 16
#define HD 128
#define HIDDEN 2048
// softmax scale folded into Q at GEMM1 epilogue: 1/sqrt(128) * log2(e)
#define QSCALE 0.12754435f
// fixed softmax offset (cancels in O = sum(p v)/sum(p)); scores |s|<~8 << 12
#define FOFF 12.0f

static __device__ __forceinline__ unsigned short f2bf(float f) {
    union { float f; unsigned int u; } c; c.f = f;
    unsigned int u = c.u;
    unsigned int rounded = u + 0x7FFF + ((u >> 16) & 1);   // RNE
    return (unsigned short)(rounded >> 16);
}

// compiler-opaque LDS read (no auto waitcnt; caller places lgkmcnt+sched_barrier)
static __device__ __forceinline__ short8 lds_read16(unsigned off) {
    short8 r;
    asm volatile("ds_read_b128 %0, %1" : "=v"(r) : "v"(off));
    return r;
}

// ---------------------------------------------------------------------------
// Elementwise cast fp32 -> bf16, 8 elements/thread
// ---------------------------------------------------------------------------
__global__ __launch_bounds__(256) void cast_f32_bf16(const float* __restrict__ src,
                                                     bf16* __restrict__ dst) {
    int i = (blockIdx.x * 256 + threadIdx.x) * 8;
    float4 a = *(const float4*)&src[i];
    float4 b = *(const float4*)&src[i + 4];
    ushort8 o;
    o[0] = f2bf(a.x); o[1] = f2bf(a.y); o[2] = f2bf(a.z); o[3] = f2bf(a.w);
    o[4] = f2bf(b.x); o[5] = f2bf(b.y); o[6] = f2bf(b.z); o[7] = f2bf(b.w);
    *(ushort8*)&dst[i] = o;
}

// ---------------------------------------------------------------------------
// Cast+transpose: dst[C x R] (bf16) = src[R x C]^T (fp32)
// ---------------------------------------------------------------------------
__global__ __launch_bounds__(256) void cast_transpose(const float* __restrict__ src,
                                                      bf16* __restrict__ dst,
                                                      int R, int C) {
    __shared__ unsigned short t[32][33];
    int tx = threadIdx.x & 31, ty = threadIdx.x >> 5;  // 32 x 8
    int c0 = blockIdx.x * 32, r0 = blockIdx.y * 32;
#pragma unroll
    for (int i = 0; i < 4; i++) {
        int r = r0 + ty + i * 8;
        t[ty + i * 8][tx] = f2bf(src[(size_t)r * C + c0 + tx]);
    }
    __syncthreads();
#pragma unroll
    for (int i = 0; i < 4; i++) {
        int cc = c0 + ty + i * 8;
        ((unsigned short*)dst)[(size_t)cc * R + r0 + tx] = t[tx][ty + i * 8];
    }
}

// ---------------------------------------------------------------------------
// Shared GEMM: 128x128 / BK=64, 256 threads (4 waves, wave-tile 64x64),
// LDS 64 KiB double-buffer -> 2 blocks/CU. MEASURED R8: merged GEMM1 135.5 us
// (R10 re-run 143.5 -- +-6% cross-run drift on unchanged kernel), MfmaUtil
// ~30-32%, conflicts 0 -- cross-block overlap (m97/m114) is the proven lever.
// FROZEN.
//   per K-tile: issue all 16 ds_reads -> lgkmcnt(4) -> 16 MFMA -> lgkmcnt(0)
//   -> 16 MFMA -> BAR -> stage(t+2) -> vmcnt(8) -> BAR.
//   EPI=0: scatter QKV epilogue. EPI=1: C = acc + bias, fp32, stride ntN*128.
// ---------------------------------------------------------------------------
#define GK 2048
#define NT 32

#define BAR __builtin_amdgcn_s_barrier()
#define SCHED0 __builtin_amdgcn_sched_barrier(0)

static __device__ __forceinline__ void gll(const bf16* g, char* l) {
    __builtin_amdgcn_global_load_lds(
        (const __attribute__((address_space(1))) void*)g,
        (__attribute__((address_space(3))) void*)l, 16, 0, 0);
}

#define STG8(s)                                                                 \
    do {                                                                        \
        _Pragma("unroll")                                                       \
        for (int ld = 0; ld < 4; ld++) {                                        \
            gll(pA + (size_t)(ld * 8) * GK + (s) * 64,                          \
                lA + ((s) & 1) * 16384 + wave * 4096 + ld * 1024);              \
            gll(pB + (size_t)(ld * 8) * GK + (s) * 64,                          \
                lB + ((s) & 1) * 16384 + wave * 4096 + ld * 1024);              \
        }                                                                       \
    } while (0)

#define RD_A(i, ks) aF[i][ks] = lds_read16(Ab + ((unsigned)((wm * 64 + (i) * 16 + lr) << 7)) + ((unsigned)(((ks) * 64 + quad * 16)) ^ axor));
#define RD_B(j, ks) bF[j][ks] = lds_read16(Bb + ((unsigned)((wn * 64 + (j) * 16 + lr) << 7)) + ((unsigned)(((ks) * 64 + quad * 16)) ^ axor));

template <int EPI>
__global__ __launch_bounds__(256, 2) void gemm128(const bf16* __restrict__ A,
                                                  const bf16* __restrict__ Bt,
                                                  const float* __restrict__ bias,
                                                  bf16* __restrict__ Qb,
                                                  bf16* __restrict__ Kb,
                                                  bf16* __restrict__ Vt,
                                                  float* __restrict__ Cout,
                                                  int ntN) {
    __shared__ __align__(16) bf16 Asm[2][128 * 64];   // 32 KiB
    __shared__ __align__(16) bf16 Bsm[2][128 * 64];   // 32 KiB

    int tid = threadIdx.x;
    int wave = tid >> 6, lane = tid & 63;
    int quad = lane >> 4, lr = lane & 15;
    int wm = wave >> 1, wn = wave & 1;
    unsigned axor = (unsigned)((lr & 7) << 4);

    // bijective XCD swizzle (gridDim.x % 8 == 0)
    int nwg = gridDim.x;
    int cpx = nwg >> 3;
    int bid = blockIdx.x;
    int swz = (bid & 7) * cpx + (bid >> 3);
    int mt = swz / ntN, nt = swz - mt * ntN;
    int m0 = mt * 128, n0 = nt * 128;

    // staging: LDS linear dest (HW adds lane*16); inverse-swizzled global src
    int srow = wave * 32 + (lane >> 3);
    int scol = ((lane & 7) ^ ((lane >> 3) & 7)) * 8;
    const bf16* pA = A + (size_t)(m0 + srow) * GK + scol;
    const bf16* pB = Bt + (size_t)(n0 + srow) * GK + scol;
    char* lA = (char*)&Asm[0][0];
    char* lB = (char*)&Bsm[0][0];

    unsigned aBase0 = (unsigned)(size_t)(__attribute__((address_space(3))) char*)lA;
    unsigned bBase0 = (unsigned)(size_t)(__attribute__((address_space(3))) char*)lB;

    const floatx4 fzero = {0.f, 0.f, 0.f, 0.f};
    floatx4 acc[4][4];
#pragma unroll
    for (int i = 0; i < 4; i++)
#pragma unroll
        for (int j = 0; j < 4; j++) acc[i][j] = fzero;

    short8 aF[4][2], bF[4][2];

    // prologue: stage K-tiles 0 and 1 (16 loads); wait first 8 (K0 landed)
    STG8(0);
    STG8(1);
    asm volatile("s_waitcnt vmcnt(8)" ::: "memory");
    BAR;

    for (int t = 0; t < NT; ++t) {
        unsigned Ab = aBase0 + (unsigned)((t & 1) * 16384);
        unsigned Bb = bBase0 + (unsigned)((t & 1) * 16384);

        // issue all 16 fragment reads: b01 (4), a0-3 (8), b23 (4)
        RD_B(0, 0) RD_B(0, 1) RD_B(1, 0) RD_B(1, 1)
        RD_A(0, 0) RD_A(0, 1) RD_A(1, 0) RD_A(1, 1)
        RD_A(2, 0) RD_A(2, 1) RD_A(3, 0) RD_A(3, 1)
        RD_B(2, 0) RD_B(2, 1) RD_B(3, 0) RD_B(3, 1)

        // oldest 12 (b01 + a) retired; b23 still draining under the MFMAs
        asm volatile("s_waitcnt lgkmcnt(4)" ::: "memory");
        SCHED0;
        __builtin_amdgcn_s_setprio(1);
#pragma unroll
        for (int ks = 0; ks < 2; ks++)
#pragma unroll
            for (int i = 0; i < 4; i++)
#pragma unroll
                for (int j = 0; j < 2; j++)
                    acc[i][j] = __builtin_amdgcn_mfma_f32_16x16x32_bf16(
                        aF[i][ks], bF[j][ks], acc[i][j], 0, 0, 0);
        __builtin_amdgcn_s_setprio(0);

        asm volatile("s_waitcnt lgkmcnt(0)" ::: "memory");
        SCHED0;
        __builtin_amdgcn_s_setprio(1);
#pragma unroll
        for (int ks = 0; ks < 2; ks++)
#pragma unroll
            for (int i = 0; i < 4; i++)
#pragma unroll
                for (int j = 2; j < 4; j++)
                    acc[i][j] = __builtin_amdgcn_mfma_f32_16x16x32_bf16(
                        aF[i][ks], bF[j][ks], acc[i][j], 0, 0, 0);
        __builtin_amdgcn_s_setprio(0);

        // all reads of tile t retired (lgkm0 above) -> safe to let stages land
        BAR;
        SCHED0;
        if (t + 2 < NT) {
            STG8(t + 2);
            SCHED0;
            asm volatile("s_waitcnt vmcnt(8)" ::: "memory");   // t+1 landed
        } else {
            asm volatile("s_waitcnt vmcnt(0)" ::: "memory");
        }
        BAR;
    }

    // ---- epilogue ----
    if (EPI == 0) {
#pragma unroll
        for (int i = 0; i < 4; i++) {
#pragma unroll
            for (int j = 0; j < 4; j++) {
                int gcn = n0 + wn * 64 + j * 16 + lr;
                float bv = bias[gcn];
                int tsel = gcn >> 11, hh = (gcn >> 7) & 15, d = gcn & 127;
#pragma unroll
                for (int reg = 0; reg < 4; reg++) {
                    int gm = m0 + wm * 64 + i * 16 + quad * 4 + reg;
                    float v = acc[i][j][reg] + bv;
                    int bb = gm >> 11, s = gm & 2047;
                    size_t hb = (size_t)(bb * NHEAD + hh);
                    if (tsel == 0) {
                        Qb[(hb * S_LEN + s) * HD + d] = __float2bfloat16(v * QSCALE);
                    } else if (tsel == 1) {
                        Kb[(hb * S_LEN + s) * HD + d] = __float2bfloat16(v);
                    } else {
                        Vt[(hb * HD + d) * S_LEN + s] = __float2bfloat16(v);
                    }
                }
            }
        }
    } else {
        int N = ntN << 7;
#pragma unroll
        for (int i = 0; i < 4; i++) {
#pragma unroll
            for (int j = 0; j < 4; j++) {
                int gcn = n0 + wn * 64 + j * 16 + lr;
                float bv = bias[gcn];
#pragma unroll
                for (int reg = 0; reg < 4; reg++) {
                    int gm = m0 + wm * 64 + i * 16 + quad * 4 + reg;
                    Cout[(size_t)gm * N + gcn] = acc[i][j][reg] + bv;
                }
            }
        }
    }
}

// ---------------------------------------------------------------------------
// Flash attention (causal), fixed-offset softmax. R11: paired grid restored
// (R10 unpaired/3-CU regressed -> occupancy is NOT attn's constraint) +
// DOUBLE-BUFFERED K/V LDS: one barrier per K-tile (was 2), commit moved
// after PV so its vmcnt wait hides under compute (T14). Per kt:
//   prefetch(kt+1)->regs | QK^T | softmax->Ps | PV | commit->buf^1 | BAR
// Hazards: buf^1 last read in iter kt-1 (retired at its barrier); sub-
// prologue commit protected by prior sub's final barrier; Ps is wave-private.
// LDS 73 KiB -> 2 blocks/CU.
// ---------------------------------------------------------------------------
#define PSTR 72   // Ps row stride (el)
__global__ __launch_bounds__(256, 2) void attn_kernel(const bf16* __restrict__ Qb,
                                                      const bf16* __restrict__ Kb,
                                                      const bf16* __restrict__ Vt,
                                                      bf16* __restrict__ Obuf) {
    __shared__ __align__(16) bf16 Ks[2][64 * 128];   // [buf][key][d], chunk^=(key&15)
    __shared__ __align__(16) bf16 Vs[2][128 * 64];   // [buf][d][key], chunk^=(d&7)
    __shared__ __align__(16) bf16 Ps[4][16 * PSTR];

    int tid = threadIdx.x;
    int wave = tid >> 6, lane = tid & 63;
    int quad = lane >> 4, lr = lane & 15;
    int srow = lane >> 4;
    int head = blockIdx.x, p = blockIdx.y, b = blockIdx.z;
    size_t hb = (size_t)(b * NHEAD + head);
    const bf16* Qbase = Qb + hb * S_LEN * HD;
    const bf16* Kbase = Kb + hb * S_LEN * HD;
    const bf16* Vbase = Vt + hb * (size_t)HD * S_LEN;

    const floatx4 fzero = {0.f, 0.f, 0.f, 0.f};
    const float MASKV = -30000.f;
    short8 ones;
#pragma unroll
    for (int i = 0; i < 8; i++) ones[i] = (short)0x3F80;   // bf16 1.0

    // prefetch tile 0 of sub 0 into registers
    ushort8 kpre[4], vpre[4];
#pragma unroll
    for (int i = 0; i < 4; i++) {
        int rl = wave * 16 + i * 4 + srow;
        int gc = lr ^ (rl & 15);
        kpre[i] = *(const ushort8*)&Kbase[(size_t)rl * HD + gc * 8];
        int vr = wave * 32 + i * 8 + (lane >> 3);
        int gvc = (lane & 7) ^ (vr & 7);
        vpre[i] = *(const ushort8*)&Vbase[(size_t)vr * S_LEN + gvc * 8];
    }

    for (int sub = 0; sub < 2; sub++) {
        int qt = sub ? (31 - p) : p;       // 64-row q-tile index, 0..31
        int q0 = qt * 64;
        int niter = qt + 1;                // diagonal tile is the last iter

        short8 qF[4];
#pragma unroll
        for (int kc = 0; kc < 4; kc++)
            qF[kc] = *(const short8*)&Qbase[(size_t)(q0 + wave * 16 + lr) * HD + kc * 32 + quad * 8];

        floatx4 Oacc[8];
        floatx4 lacc = fzero;
#pragma unroll
        for (int dn = 0; dn < 8; dn++) Oacc[dn] = fzero;

        // sub prologue: commit tile 0 into buf 0 (prior reads retired at the
        // previous sub's final iteration barrier; kernel start for sub 0)
#pragma unroll
        for (int i = 0; i < 4; i++) {
            *(ushort8*)&Ks[0][(wave * 16 + i * 4) * 128 + lane * 8] = kpre[i];
            *(ushort8*)&Vs[0][(wave * 32 + i * 8) * 64 + lane * 8] = vpre[i];
        }
        __syncthreads();

        for (int kt = 0; kt < niter; kt++) {
            int cur = kt & 1;
            const bf16* Kcur = &Ks[cur][0];
            const bf16* Vcur = &Vs[cur][0];

            // prefetch next tile (or tile 0 of sub 1) -> registers; vmcnt
            // wait lands at the commit below, hidden under QK^T+softmax+PV
            int ns0 = (kt + 1 < niter) ? (kt + 1) * 64 : (sub == 0 ? 0 : -1);
            if (ns0 >= 0) {
#pragma unroll
                for (int i = 0; i < 4; i++) {
                    int rl = wave * 16 + i * 4 + srow;
                    int gc = lr ^ (rl & 15);
                    kpre[i] = *(const ushort8*)&Kbase[(size_t)(ns0 + rl) * HD + gc * 8];
                    int vr = wave * 32 + i * 8 + (lane >> 3);
                    int gvc = (lane & 7) ^ (vr & 7);
                    vpre[i] = *(const ushort8*)&Vbase[(size_t)vr * S_LEN + ns0 + gvc * 8];
                }
            }

            // ---- QK^T: 64 keys for this wave's 16 q-rows ----
            floatx4 sc[4];
#pragma unroll
            for (int nt = 0; nt < 4; nt++) sc[nt] = fzero;
#pragma unroll
            for (int kc = 0; kc < 4; kc++)
#pragma unroll
                for (int nt = 0; nt < 4; nt++) {
                    short8 kf = *(const short8*)&Kcur[(nt * 16 + lr) * 128 + (((kc * 4 + quad) ^ lr) & 15) * 8];
                    sc[nt] = __builtin_amdgcn_mfma_f32_16x16x32_bf16(qF[kc], kf, sc[nt], 0, 0, 0);
                }
            // causal mask on the diagonal tile (last iteration; q0 == ks0)
            if (kt == niter - 1) {
#pragma unroll
                for (int nt = 0; nt < 4; nt++)
#pragma unroll
                    for (int reg = 0; reg < 4; reg++) {
                        int qg = wave * 16 + quad * 4 + reg;
                        int kg = nt * 16 + lr;
                        if (kg > qg) sc[nt][reg] = MASKV;
                    }
            }
            // ---- fixed-offset softmax: p = exp2(s - FOFF), no reductions ----
#pragma unroll
            for (int nt = 0; nt < 4; nt++)
#pragma unroll
                for (int reg = 0; reg < 4; reg++) {
                    float pv = __builtin_amdgcn_exp2f(sc[nt][reg] - FOFF);
                    Ps[wave][(quad * 4 + reg) * PSTR + nt * 16 + lr] = __float2bfloat16(pv);
                }
            // ---- PV + l accumulation via ones-MFMA ----
#pragma unroll
            for (int st = 0; st < 2; st++) {
                short8 aP = *(const short8*)&Ps[wave][lr * PSTR + st * 32 + quad * 8];
                lacc = __builtin_amdgcn_mfma_f32_16x16x32_bf16(aP, ones, lacc, 0, 0, 0);
#pragma unroll
                for (int dn = 0; dn < 8; dn++) {
                    short8 vf = *(const short8*)&Vcur[(dn * 16 + lr) * 64 + (((st * 4 + quad) ^ (lr & 7)) & 7) * 8];
                    Oacc[dn] = __builtin_amdgcn_mfma_f32_16x16x32_bf16(aP, vf, Oacc[dn], 0, 0, 0);
                }
            }

            // commit prefetched tile into the other buffer (its last readers
            // retired at iteration kt-1's barrier)
            if (kt + 1 < niter) {
#pragma unroll
                for (int i = 0; i < 4; i++) {
                    *(ushort8*)&Ks[cur ^ 1][(wave * 16 + i * 4) * 128 + lane * 8] = kpre[i];
                    *(ushort8*)&Vs[cur ^ 1][(wave * 32 + i * 8) * 64 + lane * 8] = vpre[i];
                }
            }
            __syncthreads();
        }

        // epilogue: O /= l (lacc[reg] = row-sum for row quad*4+reg, any col)
#pragma unroll
        for (int reg = 0; reg < 4; reg++) {
            float inv = 1.0f / lacc[reg];
            int qg = q0 + wave * 16 + quad * 4 + reg;
#pragma unroll
            for (int dn = 0; dn < 8; dn++) {
                int d = dn * 16 + lr;
                Obuf[((size_t)(b * S_LEN + qg)) * HIDDEN + head * HD + d] =
                    __float2bfloat16(Oacc[dn][reg] * inv);
            }
        }
    }
}

// ---------------------------------------------------------------------------
extern "C" void kernel_launch(void* const* d_in, const int* in_sizes, int n_in,
                              void* d_out, int out_size, void* d_ws, size_t ws_size,
                              hipStream_t stream) {
    (void)in_sizes; (void)n_in; (void)out_size; (void)ws_size;
    const float* x    = (const float*)d_in[0];
    const float* Wqkv = (const float*)d_in[1];
    const float* bqkv = (const float*)d_in[2];
    const float* Wo   = (const float*)d_in[3];
    const float* bo   = (const float*)d_in[4];
    float* out = (float*)d_out;

    bf16* ws = (bf16*)d_ws;
    bf16* Xb    = ws;                                   // 8.39M el
    bf16* Obuf  = ws;                                   // alias (Xb dead after GEMM1)
    bf16* WqkvT = ws + (size_t)8388608;                 // 12.58M el
    bf16* WoT   = WqkvT;                                // alias (dead after GEMM1)
    bf16* Qb    = WqkvT + (size_t)12582912;
    bf16* Kb    = Qb + (size_t)8388608;
    bf16* Vt    = Kb + (size_t)8388608;

    cast_f32_bf16<<<4096, 256, 0, stream>>>(x, Xb);
    cast_transpose<<<dim3(192, 64), 256, 0, stream>>>(Wqkv, WqkvT, 2048, 6144);
    gemm128<0><<<dim3(1536), dim3(256), 0, stream>>>(Xb, WqkvT, bqkv, Qb, Kb, Vt, nullptr, 48);
    cast_transpose<<<dim3(64, 64), 256, 0, stream>>>(Wo, WoT, 2048, 2048);
    attn_kernel<<<dim3(16, 16, 2), 256, 0, stream>>>(Qb, Kb, Vt, Obuf);
    gemm128<1><<<dim3(512), dim3(256), 0, stream>>>(Obuf, WoT, bo, nullptr, nullptr, nullptr, out, 16);
}